// Round 1
// baseline (152.890 us; speedup 1.0000x reference)
//
#include <hip/hip_runtime.h>

// RNN: h_{t+1} = relu(x_t*W_ih^T + b_ih + b_hh + W_hh·h_t), out = fc(h_T).
// B=4096, T=1000, H=20.  16 lanes per batch, 1024 waves = 1 per SIMD.
//
// Alternating-role scheme: lane (a,bq):
//   EVEN step: rows a-group x k-slice bq; reduce over bq = quad_perm folds.
//   ODD  step: rows bq-group x k-slice a; reduce over a = row_ror:4/8 folds.
// R14: rows packed (r0,r1),(r2,r3),r4 as v2f -> pk_fma.
// R16 (146.7 us baseline): splats as swizzles of live pairs (op_sel).
// R17: latency attack. VALUBusy=47% @ 1 wave/SIMD => ~74 cy/step exposed
//   dependence stall. (a) FMA accumulation split into two 3-deep chains
//   (X=input+k0+k1, Y=k2+k3+k4) + pk_add merge: serial path 9 -> 7 VALU
//   levels (+3 instr/step). (b) loop body 80 steps (~22KB) -> 40 steps
//   (~11KB): L1I-streaming derisk; prefetch distance stays 20+ steps.

#define TT 1000

typedef float v2f __attribute__((ext_vector_type(2)));

// one column k of a 5x5 tile: rows 0..4 packed as (r0,r1),(r2,r3),r4
struct Col { v2f p01, p23; float v4; };

#define PIN(v)  asm volatile("" : "+v"(v))
__device__ __forceinline__ void pinc(Col& c) {
    PIN(c.p01); PIN(c.p23); PIN(c.v4);
}
__device__ __forceinline__ void keepc(const Col& c) {
    asm volatile("" :: "v"(c.p01), "v"(c.p23), "v"(c.v4));
}

template <int CTRL>
__device__ __forceinline__ float dpp_f(float v) {
    // old=0 + bound_ctrl + full masks -> GCNDPPCombine fuses into v_add_f32_dpp
    return __int_as_float(__builtin_amdgcn_update_dpp(
        0, __float_as_int(v), CTRL, 0xF, 0xF, true));
}

#define QP_XOR1 0xB1   // quad_perm [1,0,3,2]
#define QP_XOR2 0x4E   // quad_perm [2,3,0,1]
#define ROR4   0x124   // row_ror:4  (within 16-lane row)
#define ROR8   0x128   // row_ror:8

// One timestep. xp = v2f holding 2 consecutive x's; HALF picks which one.
// h = (h01,h23,h4); columns wc0..wc4 packed by rows.
// R17: two independent accumulation chains X (input,k0,k1) and Y (k2,k3,k4),
// merged with one pk_add level. Depth 6 -> 3+1; +3 instrs.
template <int HALF, int C1, int C2>
__device__ __forceinline__ void step(v2f xp, v2f& h01, v2f& h23, float& h4,
                                     const Col& wc0, const Col& wc1,
                                     const Col& wc2, const Col& wc3,
                                     const Col& wc4,
                                     const Col& wih, const Col& bias) {
    const v2f xs = (HALF == 0) ? xp.xx : xp.yy;     // op_sel-able splat
    const float xt = (HALF == 0) ? xp.x : xp.y;

    // --- chain X: input-proj + k0 + k1
    v2f  X01 = __builtin_elementwise_fma(xs, wih.p01, bias.p01);
    v2f  X23 = __builtin_elementwise_fma(xs, wih.p23, bias.p23);
    float x4 = __builtin_fmaf(xt, wih.v4, bias.v4);

    X01 = __builtin_elementwise_fma(h01.xx, wc0.p01, X01);
    X23 = __builtin_elementwise_fma(h01.xx, wc0.p23, X23);
    x4  = __builtin_fmaf(h01.x, wc0.v4, x4);
    X01 = __builtin_elementwise_fma(h01.yy, wc1.p01, X01);
    X23 = __builtin_elementwise_fma(h01.yy, wc1.p23, X23);
    x4  = __builtin_fmaf(h01.y, wc1.v4, x4);

    // --- chain Y: k2 (pk_mul init) + k3 + k4
    v2f  Y01 = h23.xx * wc2.p01;
    v2f  Y23 = h23.xx * wc2.p23;
    float y4 = h23.x * wc2.v4;

    Y01 = __builtin_elementwise_fma(h23.yy, wc3.p01, Y01);
    Y23 = __builtin_elementwise_fma(h23.yy, wc3.p23, Y23);
    y4  = __builtin_fmaf(h23.y, wc3.v4, y4);
    { const v2f h4s = {h4, h4};
      Y01 = __builtin_elementwise_fma(h4s, wc4.p01, Y01);
      Y23 = __builtin_elementwise_fma(h4s, wc4.p23, Y23);
      y4  = __builtin_fmaf(h4, wc4.v4, y4); }

    // --- merge (one extra level, replaces 2 serial fma levels)
    v2f  A01 = X01 + Y01;      // v_pk_add_f32
    v2f  A23 = X23 + Y23;
    float a4 = x4 + y4;

    // folds on the five 32-bit halves (breadth-first: movs then adds)
    float b0 = A01.x, b1 = A01.y, b2 = A23.x, b3 = A23.y, b4 = a4;
    {
        float t0 = dpp_f<C1>(b0), t1 = dpp_f<C1>(b1), t2 = dpp_f<C1>(b2),
              t3 = dpp_f<C1>(b3), t4 = dpp_f<C1>(b4);
        b0 += t0; b1 += t1; b2 += t2; b3 += t3; b4 += t4;
    }
    {
        float t0 = dpp_f<C2>(b0), t1 = dpp_f<C2>(b1), t2 = dpp_f<C2>(b2),
              t3 = dpp_f<C2>(b3), t4 = dpp_f<C2>(b4);
        b0 += t0; b1 += t1; b2 += t2; b3 += t3; b4 += t4;
    }

    const v2f z = {0.f, 0.f};
    v2f r01 = {b0, b1};
    v2f r23 = {b2, b3};
    h01 = __builtin_elementwise_max(r01, z);   // v_pk_max_f32
    h23 = __builtin_elementwise_max(r23, z);
    h4  = fmaxf(b4, 0.f);
}

__global__ void
__attribute__((amdgpu_flat_work_group_size(64, 64), amdgpu_waves_per_eu(1, 1)))
rnn_os_kernel(const float* __restrict__ x,
              const float* __restrict__ W_ih,
              const float* __restrict__ W_hh,
              const float* __restrict__ b_ih,
              const float* __restrict__ b_hh,
              const float* __restrict__ fc_w,
              const float* __restrict__ fc_b,
              float* __restrict__ out) {
    const int tid = blockIdx.x * 64 + threadIdx.x;
    const int b   = tid >> 4;     // batch element
    const int gl  = tid & 15;     // lane in 16-lane group
    const int a   = gl >> 2;      // quad index
    const int bq  = gl & 3;       // position in quad

    // --- weight tiles, column-major, packed rows
    Col we0, we1, we2, we3, we4;  // even: rows a-group, cols bq-group
    Col wo0, wo1, wo2, wo3, wo4;  // odd:  rows bq-group, cols a-group
#define LOADC(wk, k, rbase, cbase)                                            \
    { (wk).p01 = (v2f){ W_hh[((rbase) + 0) * 20 + (cbase) + (k)],             \
                        W_hh[((rbase) + 1) * 20 + (cbase) + (k)] };           \
      (wk).p23 = (v2f){ W_hh[((rbase) + 2) * 20 + (cbase) + (k)],             \
                        W_hh[((rbase) + 3) * 20 + (cbase) + (k)] };           \
      (wk).v4  =        W_hh[((rbase) + 4) * 20 + (cbase) + (k)]; }
    LOADC(we0, 0, a * 5, bq * 5) LOADC(we1, 1, a * 5, bq * 5)
    LOADC(we2, 2, a * 5, bq * 5) LOADC(we3, 3, a * 5, bq * 5)
    LOADC(we4, 4, a * 5, bq * 5)
    LOADC(wo0, 0, bq * 5, a * 5) LOADC(wo1, 1, bq * 5, a * 5)
    LOADC(wo2, 2, bq * 5, a * 5) LOADC(wo3, 3, bq * 5, a * 5)
    LOADC(wo4, 4, bq * 5, a * 5)
#undef LOADC

    const bool eact = (bq == 0);  // even steps: reduction over bq
    const bool oact = (a == 0);   // odd steps:  reduction over a
    Col wie, bie, wio, bio;
#define LOADIB(wv, bv, base, act)                                             \
    { const float* pw = W_ih + (base);                                        \
      const float* p1 = b_ih + (base);                                        \
      const float* p2 = b_hh + (base);                                        \
      (wv).p01 = (v2f){ (act) ? pw[0] : 0.f, (act) ? pw[1] : 0.f };           \
      (wv).p23 = (v2f){ (act) ? pw[2] : 0.f, (act) ? pw[3] : 0.f };           \
      (wv).v4  =        (act) ? pw[4] : 0.f;                                  \
      (bv).p01 = (v2f){ (act) ? (p1[0] + p2[0]) : 0.f,                        \
                        (act) ? (p1[1] + p2[1]) : 0.f };                      \
      (bv).p23 = (v2f){ (act) ? (p1[2] + p2[2]) : 0.f,                        \
                        (act) ? (p1[3] + p2[3]) : 0.f };                      \
      (bv).v4  =        (act) ? (p1[4] + p2[4]) : 0.f; }
    LOADIB(wie, bie, a * 5,  eact)
    LOADIB(wio, bio, bq * 5, oact)
#undef LOADIB

    pinc(we0); pinc(we1); pinc(we2); pinc(we3); pinc(we4);
    pinc(wo0); pinc(wo1); pinc(wo2); pinc(wo3); pinc(wo4);
    pinc(wie); pinc(bie); pinc(wio); pinc(bio);

    v2f h01 = {0.f, 0.f}, h23 = {0.f, 0.f};
    float h4 = 0.f;

    const float* __restrict__ xb = x + (size_t)b * TT;

    // --- 20-step register blocks (5 float4 each), double-buffered.
    // 50 blocks of 20 steps; loop runs 2 blocks (40 steps) per iteration,
    // prefetching the next pair. Body ~11 KB (vs 22 KB in R16).
#define LOAD5(P, off)                                   \
    P##0 = *(const float4*)(xb + (off));                \
    P##1 = *(const float4*)(xb + (off) + 4);            \
    P##2 = *(const float4*)(xb + (off) + 8);            \
    P##3 = *(const float4*)(xb + (off) + 12);           \
    P##4 = *(const float4*)(xb + (off) + 16);

#define STEP_E(xp, H) step<H, QP_XOR1, QP_XOR2>(xp, h01, h23, h4, we0, we1, we2, we3, we4, wie, bie);
#define STEP_O(xp, H) step<H, ROR4,    ROR8   >(xp, h01, h23, h4, wo0, wo1, wo2, wo3, wo4, wio, bio);
#define RUN4(Q) {                                       \
        const v2f qlo = {Q.x, Q.y};                     \
        const v2f qhi = {Q.z, Q.w};                     \
        STEP_E(qlo, 0) STEP_O(qlo, 1)                   \
        STEP_E(qhi, 0) STEP_O(qhi, 1) }
#define RUN20(P) RUN4(P##0) RUN4(P##1) RUN4(P##2) RUN4(P##3) RUN4(P##4)

    float4 A0, A1, A2, A3, A4;
    float4 B0, B1, B2, B3, B4;
    LOAD5(A, 0)    // block 0: steps 0..19
    LOAD5(B, 20)   // block 1: steps 20..39

    // 24 iterations x 40 steps = 960, then blocks 48,49 as the tail.
    // Loads: iter it fetches blocks 2it+2 and 2it+3; it=23 fetches
    // blocks 48 (steps 960..979) and 49 (980..999) -- always in-bounds.
    for (int it = 0; it < 24; ++it) {
        const int base = it * 40;
        RUN20(A)                    // steps base .. base+19
        LOAD5(A, base + 40)         // block 2it+2
        RUN20(B)                    // steps base+20 .. base+39
        LOAD5(B, base + 60)         // block 2it+3
    }
    RUN20(A)                        // steps 960..979
    RUN20(B)                        // steps 980..999

#undef RUN20
#undef RUN4
#undef STEP_E
#undef STEP_O
#undef LOAD5

    keepc(we0); keepc(we1); keepc(we2); keepc(we3); keepc(we4);
    keepc(wo0); keepc(wo1); keepc(wo2); keepc(wo3); keepc(wo4);
    keepc(wie); keepc(bie); keepc(wio); keepc(bio);

    // After step 999 (odd role), lane (a,bq) holds h[bq-slice] replicated
    // over a. Mask fc weights to a==0 lanes, dot, reduce across the group.
    float dot;
    {
        const float* pf = fc_w + bq * 5;
        float f0 = oact ? pf[0] : 0.f, f1 = oact ? pf[1] : 0.f;
        float f2 = oact ? pf[2] : 0.f, f3 = oact ? pf[3] : 0.f;
        float f4 = oact ? pf[4] : 0.f;
        dot = h01.x * f0;
        dot = __builtin_fmaf(h01.y, f1, dot);
        dot = __builtin_fmaf(h23.x, f2, dot);
        dot = __builtin_fmaf(h23.y, f3, dot);
        dot = __builtin_fmaf(h4,    f4, dot);
    }
    dot += __shfl_xor(dot, 1, 16);
    dot += __shfl_xor(dot, 2, 16);
    dot += __shfl_xor(dot, 4, 16);
    dot += __shfl_xor(dot, 8, 16);

    if (gl == 0)
        out[b] = dot + fc_b[0];
}

extern "C" void kernel_launch(void* const* d_in, const int* in_sizes, int n_in,
                              void* d_out, int out_size, void* d_ws, size_t ws_size,
                              hipStream_t stream) {
    const float* x    = (const float*)d_in[0];
    const float* W_ih = (const float*)d_in[1];
    const float* W_hh = (const float*)d_in[2];
    const float* b_ih = (const float*)d_in[3];
    const float* b_hh = (const float*)d_in[4];
    const float* fc_w = (const float*)d_in[5];
    const float* fc_b = (const float*)d_in[6];
    float* out = (float*)d_out;

    // 4096 batches * 16 lanes = 65536 threads; 64-thread blocks -> 1024
    // single-wave blocks, one per SIMD.
    const int block = 64;
    const int grid  = (4096 * 16) / block;  // 1024 blocks
    rnn_os_kernel<<<grid, block, 0, stream>>>(x, W_ih, W_hh, b_ih, b_hh,
                                              fc_w, fc_b, out);
}

// Round 2
// 152.167 us; speedup vs baseline: 1.0048x; 1.0048x over previous
//
#include <hip/hip_runtime.h>

// RNN: h_{t+1} = relu(x_t*W_ih^T + b_ih + b_hh + W_hh·h_t), out = fc(h_T).
// B=4096, T=1000, H=20.  16 lanes per batch, 1024 waves = 1 per SIMD.
//
// Alternating-role scheme: lane (a,bq):
//   EVEN step: rows a-group x k-slice bq; reduce over bq = quad_perm folds.
//   ODD  step: rows bq-group x k-slice a; reduce over a = row_ror:4/8 folds.
// R14: rows packed (r0,r1),(r2,r3),r4 as v2f -> pk_fma.
// R16 (135.6us rocprof): splats as swizzles of live pairs (op_sel).
// R17 (96.6us rocprof, VALUBusy 72%): X/Y chain split, depth 9 -> 7 levels.
// R18: tail stagger. Remaining ~30cy/step stall = DPP read-after-VALU
//   hazard nops + lockstep tail (h01/h23/h4 finish together -> next head
//   can't start). (a) depth-first per-pair finalize: h01 completes first,
//   next step's k0/k1 FMAs overlap the b2..b4 folds; (b) input-proj inits
//   hoisted to RUN4 top as guaranteed tail filler. Sum order == R17.

#define TT 1000

typedef float v2f __attribute__((ext_vector_type(2)));

// one column k of a 5x5 tile: rows 0..4 packed as (r0,r1),(r2,r3),r4
struct Col { v2f p01, p23; float v4; };

// precomputed input projection x*W_ih + (b_ih+b_hh) for one step
struct Init { v2f i01, i23; float i4; };

#define PIN(v)  asm volatile("" : "+v"(v))
__device__ __forceinline__ void pinc(Col& c) {
    PIN(c.p01); PIN(c.p23); PIN(c.v4);
}
__device__ __forceinline__ void keepc(const Col& c) {
    asm volatile("" :: "v"(c.p01), "v"(c.p23), "v"(c.v4));
}

template <int CTRL>
__device__ __forceinline__ float dpp_f(float v) {
    // old=0 + bound_ctrl + full masks -> GCNDPPCombine fuses into v_add_f32_dpp
    return __int_as_float(__builtin_amdgcn_update_dpp(
        0, __float_as_int(v), CTRL, 0xF, 0xF, true));
}

#define QP_XOR1 0xB1   // quad_perm [1,0,3,2]
#define QP_XOR2 0x4E   // quad_perm [2,3,0,1]
#define ROR4   0x124   // row_ror:4  (within 16-lane row)
#define ROR8   0x128   // row_ror:8

__device__ __forceinline__ Init mkinit(v2f xs, float xt,
                                       const Col& w, const Col& b) {
    Init r;
    r.i01 = __builtin_elementwise_fma(xs, w.p01, b.p01);
    r.i23 = __builtin_elementwise_fma(xs, w.p23, b.p23);
    r.i4  = __builtin_fmaf(xt, w.v4, b.v4);
    return r;
}

// One timestep from a precomputed init. Two chains:
//   X = k0,k1 onto init (2 levels from h01); Y = k2(mul),k3,k4 (3 levels).
// Tail finalized DEPTH-FIRST per pair so h01 is ready earliest.
template <int C1, int C2>
__device__ __forceinline__ void step(const Init& in,
                                     v2f& h01, v2f& h23, float& h4,
                                     const Col& wc0, const Col& wc1,
                                     const Col& wc2, const Col& wc3,
                                     const Col& wc4) {
    // --- chain X (h01-dependent)
    v2f  X01 = __builtin_elementwise_fma(h01.xx, wc0.p01, in.i01);
    v2f  X23 = __builtin_elementwise_fma(h01.xx, wc0.p23, in.i23);
    float x4 = __builtin_fmaf(h01.x, wc0.v4, in.i4);
    X01 = __builtin_elementwise_fma(h01.yy, wc1.p01, X01);
    X23 = __builtin_elementwise_fma(h01.yy, wc1.p23, X23);
    x4  = __builtin_fmaf(h01.y, wc1.v4, x4);

    // --- chain Y (h23/h4-dependent)
    v2f  Y01 = h23.xx * wc2.p01;
    v2f  Y23 = h23.xx * wc2.p23;
    float y4 = h23.x * wc2.v4;
    Y01 = __builtin_elementwise_fma(h23.yy, wc3.p01, Y01);
    Y23 = __builtin_elementwise_fma(h23.yy, wc3.p23, Y23);
    y4  = __builtin_fmaf(h23.y, wc3.v4, y4);
    { const v2f h4s = {h4, h4};
      Y01 = __builtin_elementwise_fma(h4s, wc4.p01, Y01);
      Y23 = __builtin_elementwise_fma(h4s, wc4.p23, Y23);
      y4  = __builtin_fmaf(h4, wc4.v4, y4); }

    const v2f z = {0.f, 0.f};

    // --- pair 01: merge -> fold -> relu (h01 ready first; next step's
    //     k0/k1 FMAs can overlap the remaining folds below)
    {
        v2f A = X01 + Y01;                 // v_pk_add_f32
        float b0 = A.x, b1 = A.y;
        float t0 = dpp_f<C1>(b0), t1 = dpp_f<C1>(b1);
        b0 += t0; b1 += t1;
        t0 = dpp_f<C2>(b0); t1 = dpp_f<C2>(b1);
        b0 += t0; b1 += t1;
        v2f r = {b0, b1};
        h01 = __builtin_elementwise_max(r, z);   // v_pk_max_f32
    }
    // --- pair 23
    {
        v2f A = X23 + Y23;
        float b2 = A.x, b3 = A.y;
        float t2 = dpp_f<C1>(b2), t3 = dpp_f<C1>(b3);
        b2 += t2; b3 += t3;
        t2 = dpp_f<C2>(b2); t3 = dpp_f<C2>(b3);
        b2 += t2; b3 += t3;
        v2f r = {b2, b3};
        h23 = __builtin_elementwise_max(r, z);
    }
    // --- row 4
    {
        float b4 = x4 + y4;
        float t4 = dpp_f<C1>(b4); b4 += t4;
        t4 = dpp_f<C2>(b4); b4 += t4;
        h4 = fmaxf(b4, 0.f);
    }
}

__global__ void
__attribute__((amdgpu_flat_work_group_size(64, 64), amdgpu_waves_per_eu(1, 1)))
rnn_os_kernel(const float* __restrict__ x,
              const float* __restrict__ W_ih,
              const float* __restrict__ W_hh,
              const float* __restrict__ b_ih,
              const float* __restrict__ b_hh,
              const float* __restrict__ fc_w,
              const float* __restrict__ fc_b,
              float* __restrict__ out) {
    const int tid = blockIdx.x * 64 + threadIdx.x;
    const int b   = tid >> 4;     // batch element
    const int gl  = tid & 15;     // lane in 16-lane group
    const int a   = gl >> 2;      // quad index
    const int bq  = gl & 3;       // position in quad

    // --- weight tiles, column-major, packed rows
    Col we0, we1, we2, we3, we4;  // even: rows a-group, cols bq-group
    Col wo0, wo1, wo2, wo3, wo4;  // odd:  rows bq-group, cols a-group
#define LOADC(wk, k, rbase, cbase)                                            \
    { (wk).p01 = (v2f){ W_hh[((rbase) + 0) * 20 + (cbase) + (k)],             \
                        W_hh[((rbase) + 1) * 20 + (cbase) + (k)] };           \
      (wk).p23 = (v2f){ W_hh[((rbase) + 2) * 20 + (cbase) + (k)],             \
                        W_hh[((rbase) + 3) * 20 + (cbase) + (k)] };           \
      (wk).v4  =        W_hh[((rbase) + 4) * 20 + (cbase) + (k)]; }
    LOADC(we0, 0, a * 5, bq * 5) LOADC(we1, 1, a * 5, bq * 5)
    LOADC(we2, 2, a * 5, bq * 5) LOADC(we3, 3, a * 5, bq * 5)
    LOADC(we4, 4, a * 5, bq * 5)
    LOADC(wo0, 0, bq * 5, a * 5) LOADC(wo1, 1, bq * 5, a * 5)
    LOADC(wo2, 2, bq * 5, a * 5) LOADC(wo3, 3, bq * 5, a * 5)
    LOADC(wo4, 4, bq * 5, a * 5)
#undef LOADC

    const bool eact = (bq == 0);  // even steps: reduction over bq
    const bool oact = (a == 0);   // odd steps:  reduction over a
    Col wie, bie, wio, bio;
#define LOADIB(wv, bv, base, act)                                             \
    { const float* pw = W_ih + (base);                                        \
      const float* p1 = b_ih + (base);                                        \
      const float* p2 = b_hh + (base);                                        \
      (wv).p01 = (v2f){ (act) ? pw[0] : 0.f, (act) ? pw[1] : 0.f };           \
      (wv).p23 = (v2f){ (act) ? pw[2] : 0.f, (act) ? pw[3] : 0.f };           \
      (wv).v4  =        (act) ? pw[4] : 0.f;                                  \
      (bv).p01 = (v2f){ (act) ? (p1[0] + p2[0]) : 0.f,                        \
                        (act) ? (p1[1] + p2[1]) : 0.f };                      \
      (bv).p23 = (v2f){ (act) ? (p1[2] + p2[2]) : 0.f,                        \
                        (act) ? (p1[3] + p2[3]) : 0.f };                      \
      (bv).v4  =        (act) ? (p1[4] + p2[4]) : 0.f; }
    LOADIB(wie, bie, a * 5,  eact)
    LOADIB(wio, bio, bq * 5, oact)
#undef LOADIB

    pinc(we0); pinc(we1); pinc(we2); pinc(we3); pinc(we4);
    pinc(wo0); pinc(wo1); pinc(wo2); pinc(wo3); pinc(wo4);
    pinc(wie); pinc(bie); pinc(wio); pinc(bio);

    v2f h01 = {0.f, 0.f}, h23 = {0.f, 0.f};
    float h4 = 0.f;

    const float* __restrict__ xb = x + (size_t)b * TT;

    // --- 20-step register blocks (5 float4 each), double-buffered.
#define LOAD5(P, off)                                   \
    P##0 = *(const float4*)(xb + (off));                \
    P##1 = *(const float4*)(xb + (off) + 4);            \
    P##2 = *(const float4*)(xb + (off) + 8);            \
    P##3 = *(const float4*)(xb + (off) + 12);           \
    P##4 = *(const float4*)(xb + (off) + 16);

#define STEP_E(I) step<QP_XOR1, QP_XOR2>(I, h01, h23, h4, we0, we1, we2, we3, we4);
#define STEP_O(I) step<ROR4,    ROR8   >(I, h01, h23, h4, wo0, wo1, wo2, wo3, wo4);
    // 4 steps per float4: inits (h-independent) hoisted up front so the
    // scheduler has filler for the fold/DPP tail of every step.
#define RUN4(Q) {                                       \
        const v2f qlo = {Q.x, Q.y};                     \
        const v2f qhi = {Q.z, Q.w};                     \
        const Init iEL = mkinit(qlo.xx, qlo.x, wie, bie); \
        const Init iOL = mkinit(qlo.yy, qlo.y, wio, bio); \
        const Init iEH = mkinit(qhi.xx, qhi.x, wie, bie); \
        const Init iOH = mkinit(qhi.yy, qhi.y, wio, bio); \
        STEP_E(iEL) STEP_O(iOL)                         \
        STEP_E(iEH) STEP_O(iOH) }
#define RUN20(P) RUN4(P##0) RUN4(P##1) RUN4(P##2) RUN4(P##3) RUN4(P##4)

    float4 A0, A1, A2, A3, A4;
    float4 B0, B1, B2, B3, B4;
    LOAD5(A, 0)    // block 0: steps 0..19
    LOAD5(B, 20)   // block 1: steps 20..39

    // 24 iterations x 40 steps = 960, then blocks 48,49 as the tail.
    // Loads: iter it fetches blocks 2it+2 and 2it+3; it=23 fetches
    // blocks 48 (steps 960..979) and 49 (980..999) -- always in-bounds.
    for (int it = 0; it < 24; ++it) {
        const int base = it * 40;
        RUN20(A)                    // steps base .. base+19
        LOAD5(A, base + 40)         // block 2it+2
        RUN20(B)                    // steps base+20 .. base+39
        LOAD5(B, base + 60)         // block 2it+3
    }
    RUN20(A)                        // steps 960..979
    RUN20(B)                        // steps 980..999

#undef RUN20
#undef RUN4
#undef STEP_E
#undef STEP_O
#undef LOAD5

    keepc(we0); keepc(we1); keepc(we2); keepc(we3); keepc(we4);
    keepc(wo0); keepc(wo1); keepc(wo2); keepc(wo3); keepc(wo4);
    keepc(wie); keepc(bie); keepc(wio); keepc(bio);

    // After step 999 (odd role), lane (a,bq) holds h[bq-slice] replicated
    // over a. Mask fc weights to a==0 lanes, dot, reduce across the group.
    float dot;
    {
        const float* pf = fc_w + bq * 5;
        float f0 = oact ? pf[0] : 0.f, f1 = oact ? pf[1] : 0.f;
        float f2 = oact ? pf[2] : 0.f, f3 = oact ? pf[3] : 0.f;
        float f4 = oact ? pf[4] : 0.f;
        dot = h01.x * f0;
        dot = __builtin_fmaf(h01.y, f1, dot);
        dot = __builtin_fmaf(h23.x, f2, dot);
        dot = __builtin_fmaf(h23.y, f3, dot);
        dot = __builtin_fmaf(h4,    f4, dot);
    }
    dot += __shfl_xor(dot, 1, 16);
    dot += __shfl_xor(dot, 2, 16);
    dot += __shfl_xor(dot, 4, 16);
    dot += __shfl_xor(dot, 8, 16);

    if (gl == 0)
        out[b] = dot + fc_b[0];
}

extern "C" void kernel_launch(void* const* d_in, const int* in_sizes, int n_in,
                              void* d_out, int out_size, void* d_ws, size_t ws_size,
                              hipStream_t stream) {
    const float* x    = (const float*)d_in[0];
    const float* W_ih = (const float*)d_in[1];
    const float* W_hh = (const float*)d_in[2];
    const float* b_ih = (const float*)d_in[3];
    const float* b_hh = (const float*)d_in[4];
    const float* fc_w = (const float*)d_in[5];
    const float* fc_b = (const float*)d_in[6];
    float* out = (float*)d_out;

    // 4096 batches * 16 lanes = 65536 threads; 64-thread blocks -> 1024
    // single-wave blocks, one per SIMD.
    const int block = 64;
    const int grid  = (4096 * 16) / block;  // 1024 blocks
    rnn_os_kernel<<<grid, block, 0, stream>>>(x, W_ih, W_hh, b_ih, b_hh,
                                              fc_w, fc_b, out);
}